// Round 1
// baseline (3051.090 us; speedup 1.0000x reference)
//
#include <hip/hip_runtime.h>
#include <cmath>

#define TID ((int)threadIdx.x)

constexpr int N_IN = 10000;
constexpr int HI   = 128;
constexpr int HH   = 512;
constexpr int TT   = 16;
constexpr int XP   = 10001;   // x row pitch (N+1)
constexpr int XCP  = 132;     // xc row pitch (128 + weight + pad)
constexpr int KTOT = 641;     // 129 + 512
constexpr int G4   = 2048;

__device__ __forceinline__ float sigm(float x) { return 1.0f / (1.0f + expf(-x)); }

// ---------------- kernel A: xc[row][0:128] = x[row][0:N] @ W_down, xc[row][128] = x[row][N]
// grid 256 row-tiles of 32, block 128 threads (2 waves), 8x4 per-thread tile
constexpr int A_KB = 80;   // 10000 = 80*125 exact
__global__ __launch_bounds__(128)
void kA_downproj(const float* __restrict__ x, const float* __restrict__ Wd,
                 float* __restrict__ xc) {
  __shared__ float At[A_KB][32];    // [kk][row] transposed A tile
  __shared__ float Wt[A_KB][HI];    // [kk][col]
  const int row0 = blockIdx.x * 32;
  const int tx = TID & 31, ty = TID >> 5;
  const int r0 = ty * 8, c0 = tx * 4;
  float acc[8][4] = {};
  for (int k0 = 0; k0 < N_IN; k0 += A_KB) {
    // stage A: 32 rows x 80 k = 2560 floats, 20/thread; lanes->r (conflict-free LDS writes)
    #pragma unroll
    for (int i = 0; i < 20; ++i) {
      int f = TID + 128 * i;
      int kk = f >> 5, r = f & 31;
      At[kk][r] = x[(size_t)(row0 + r) * XP + k0 + kk];
    }
    // stage W: 80 x 128 = 2560 float4, 20/thread, coalesced
    #pragma unroll
    for (int i = 0; i < 20; ++i) {
      int f = TID + 128 * i;
      int kk = f >> 5, c4 = (f & 31) * 4;
      *(float4*)&Wt[kk][c4] = *(const float4*)&Wd[(size_t)(k0 + kk) * HI + c4];
    }
    __syncthreads();
    #pragma unroll 4
    for (int kk = 0; kk < A_KB; ++kk) {
      float4 a0 = *(const float4*)&At[kk][r0];
      float4 a1 = *(const float4*)&At[kk][r0 + 4];
      float4 w  = *(const float4*)&Wt[kk][c0];
      float ar[8] = {a0.x,a0.y,a0.z,a0.w,a1.x,a1.y,a1.z,a1.w};
      float wr[4] = {w.x,w.y,w.z,w.w};
      #pragma unroll
      for (int e = 0; e < 8; ++e)
        #pragma unroll
        for (int g = 0; g < 4; ++g)
          acc[e][g] += ar[e] * wr[g];
    }
    __syncthreads();
  }
  #pragma unroll
  for (int e = 0; e < 8; ++e) {
    float4 v = make_float4(acc[e][0], acc[e][1], acc[e][2], acc[e][3]);
    *(float4*)&xc[(size_t)(row0 + r0 + e) * XCP + c0] = v;
  }
  if (TID < 32) {   // append the per-(b,t) scalar weight at col 128
    size_t r = (size_t)row0 + TID;
    xc[r * XCP + 128] = x[r * XP + N_IN];
  }
}

// ---------------- kernel B: one LSTM step (fused gates GEMM + pointwise)
// gates[b][g*512+j] = sum_k concat(xc_t, h)[b][k] * Wc[k][g*512+j] + bc
// grid (16 j-tiles, 16 b-tiles), block 128 threads, per-thread 8 rows x 1 j x 4 gates
constexpr int S_KB = 64;
__global__ __launch_bounds__(128)
void kB_step(const float* __restrict__ xc, const float* __restrict__ Wc,
             const float* __restrict__ bc, const float* __restrict__ h_in,
             const float* __restrict__ c_in, float* __restrict__ h_out,
             float* __restrict__ c_out, int t, int is_first) {
  __shared__ float At[S_KB][32];    // [kk][b] transposed input tile
  __shared__ float Wt[S_KB][128];   // [kk][jj*4+g] gate-interleaved
  const int j0 = blockIdx.x * 32, b0 = blockIdx.y * 32;
  const int jj = TID & 31, ty = TID >> 5;
  const int r0 = ty * 8;
  float acc[8][4] = {};
  const int kend = is_first ? 192 : 704;   // 704 = 11*64 >= 641 (zero-padded tail)
  for (int k0 = 0; k0 < kend; k0 += S_KB) {
    // stage A: 64 kk x 32 b = 2048 floats, 16/thread; lanes->r conflict-free
    #pragma unroll
    for (int i = 0; i < 16; ++i) {
      int f = TID + 128 * i;
      int kk = f >> 5, r = f & 31;
      int k = k0 + kk;
      float v = 0.0f;
      if (k < 129)                       v = xc[((size_t)(b0 + r) * TT + t) * XCP + k];
      else if (k < KTOT && !is_first)    v = h_in[(size_t)(b0 + r) * HH + (k - 129)];
      At[kk][r] = v;
    }
    // stage W: 64 kk x (32 j x 4 gates) = 8192 floats, 64/thread; LDS col = jj*4+g
    #pragma unroll 4
    for (int i = 0; i < 64; ++i) {
      int f = TID + 128 * i;
      int kk = f >> 7, c = f & 127;
      int k = k0 + kk;
      Wt[kk][c] = (k < KTOT) ? Wc[(size_t)k * G4 + (c & 3) * HH + j0 + (c >> 2)] : 0.0f;
    }
    __syncthreads();
    #pragma unroll 4
    for (int kk = 0; kk < S_KB; ++kk) {
      float4 a0 = *(const float4*)&At[kk][r0];
      float4 a1 = *(const float4*)&At[kk][r0 + 4];
      float4 w  = *(const float4*)&Wt[kk][jj * 4];
      float ar[8] = {a0.x,a0.y,a0.z,a0.w,a1.x,a1.y,a1.z,a1.w};
      float wr[4] = {w.x,w.y,w.z,w.w};
      #pragma unroll
      for (int e = 0; e < 8; ++e)
        #pragma unroll
        for (int g = 0; g < 4; ++g)
          acc[e][g] += ar[e] * wr[g];
    }
    __syncthreads();
  }
  const int j = j0 + jj;
  const float bi = bc[j], bg = bc[HH + j], bf = bc[2 * HH + j], bo = bc[3 * HH + j];
  #pragma unroll
  for (int e = 0; e < 8; ++e) {
    int b = b0 + r0 + e;
    float gi = acc[e][0] + bi;
    float gc = acc[e][1] + bg;
    float gf = acc[e][2] + bf;
    float go = acc[e][3] + bo;
    float cp = is_first ? 0.0f : c_in[(size_t)b * HH + j];
    float cn = cp * sigm(gf + 1.0f) + sigm(gi) * tanhf(gc);
    float hn = sigm(go) * tanhf(cn);
    c_out[(size_t)b * HH + j] = cn;
    h_out[(size_t)b * HH + j] = hn;
  }
}

// ---------------- kernel C: pred[b] = h[b] . W_out + b_out
__global__ __launch_bounds__(64)
void kC_out(const float* __restrict__ h, const float* __restrict__ Wo,
            const float* __restrict__ bo, float* __restrict__ out) {
  const int b = blockIdx.x;
  float s = 0.0f;
  #pragma unroll
  for (int j = TID; j < HH; j += 64) s += h[(size_t)b * HH + j] * Wo[j];
  #pragma unroll
  for (int off = 32; off > 0; off >>= 1) s += __shfl_down(s, off);
  if (TID == 0) out[b] = s + bo[0];
}

extern "C" void kernel_launch(void* const* d_in, const int* in_sizes, int n_in,
                              void* d_out, int out_size, void* d_ws, size_t ws_size,
                              hipStream_t stream) {
  const float* x  = (const float*)d_in[0];
  const float* Wd = (const float*)d_in[1];
  const float* Wc = (const float*)d_in[2];
  const float* bc = (const float*)d_in[3];
  const float* Wo = (const float*)d_in[4];
  const float* bo = (const float*)d_in[5];
  float* out = (float*)d_out;
  float* ws  = (float*)d_ws;

  float* xc = ws;                                  // 8192 * 132 floats
  float* base = xc + (size_t)8192 * XCP;
  float* hb[2] = { base,               base + 262144 };
  float* cb[2] = { base + 2 * 262144,  base + 3 * 262144 };

  kA_downproj<<<256, 128, 0, stream>>>(x, Wd, xc);
  for (int t = 0; t < TT; ++t) {
    kB_step<<<dim3(16, 16), 128, 0, stream>>>(xc, Wc, bc,
        hb[t & 1], cb[t & 1], hb[(t + 1) & 1], cb[(t + 1) & 1], t, (t == 0) ? 1 : 0);
  }
  kC_out<<<512, 64, 0, stream>>>(hb[0], Wo, bo, out);
}

// Round 2
// 661.589 us; speedup vs baseline: 4.6118x; 4.6118x over previous
//
#include <hip/hip_runtime.h>
#include <cmath>

#define TID ((int)threadIdx.x)

typedef __bf16 bf16_t;
typedef bf16_t bf16x8 __attribute__((ext_vector_type(8)));
typedef float floatx4 __attribute__((ext_vector_type(4)));

#define MFMA(a, b, c) __builtin_amdgcn_mfma_f32_16x16x32_bf16(a, b, c, 0, 0, 0)

constexpr int N_IN = 10000;
constexpr int XP   = 10001;   // x row pitch
constexpr int KPD  = 10240;   // padded K for W_down^T (multiple of 64)
constexpr int HH   = 512;
constexpr int TT   = 16;
constexpr int NB   = 512;     // batch
constexpr int MROW = 8192;    // NB*TT
constexpr int KSPLIT = 8;
constexpr int KCHUNK = 1280;  // KPD / KSPLIT

__device__ __forceinline__ float sigm(float x) { return 1.0f / (1.0f + expf(-x)); }

// ---------- prep: W_down (10000x128 fp32) -> WdT hi/lo bf16 [128][10240]
__global__ __launch_bounds__(256)
void kPrepWd(const float* __restrict__ Wd, bf16_t* __restrict__ Whi, bf16_t* __restrict__ Wlo) {
  __shared__ float Ts[64][133];
  const int k0 = blockIdx.x * 64;
  #pragma unroll
  for (int i = 0; i < 32; ++i) {
    int f = TID + 256 * i;
    int kk = f >> 7, c = f & 127;
    int k = k0 + kk;
    Ts[kk][c] = (k < N_IN) ? Wd[(size_t)k * 128 + c] : 0.0f;
  }
  __syncthreads();
  const int lane = TID & 63, w = TID >> 6;
  for (int pass = 0; pass < 32; ++pass) {
    int c = pass * 4 + w;
    float v = Ts[lane][c];
    bf16_t hi = (bf16_t)v;
    bf16_t lo = (bf16_t)(v - (float)hi);
    Whi[(size_t)c * KPD + k0 + lane] = hi;
    Wlo[(size_t)c * KPD + k0 + lane] = lo;
  }
}

// ---------- prep: W_cell (641x2048) -> WxT[2048][128], wN[2048], WhT[2048][512] (hi/lo)
__global__ __launch_bounds__(256)
void kPrepWc(const float* __restrict__ Wc, bf16_t* __restrict__ Wxh, bf16_t* __restrict__ Wxl,
             float* __restrict__ wN, bf16_t* __restrict__ Whh, bf16_t* __restrict__ Whl) {
  __shared__ float Ts[64][133];
  const int k0 = blockIdx.x * 64;
  const int c0 = blockIdx.y * 128;
  #pragma unroll
  for (int i = 0; i < 32; ++i) {
    int f = TID + 256 * i;
    int kk = f >> 7, cc = f & 127;
    int k = k0 + kk;
    Ts[kk][cc] = (k < 641) ? Wc[(size_t)k * 2048 + c0 + cc] : 0.0f;
  }
  __syncthreads();
  const int lane = TID & 63, w = TID >> 6;
  const int k = k0 + lane;
  for (int pass = 0; pass < 32; ++pass) {
    int cc = pass * 4 + w;
    int c = c0 + cc;
    float v = Ts[lane][cc];
    bf16_t hi = (bf16_t)v;
    bf16_t lo = (bf16_t)(v - (float)hi);
    if (k < 128) {
      Wxh[(size_t)c * 128 + k] = hi;
      Wxl[(size_t)c * 128 + k] = lo;
    } else if (k == 128) {
      wN[c] = v;
    } else if (k < 641) {
      Whh[(size_t)c * 512 + (k - 129)] = hi;
      Whl[(size_t)c * 512 + (k - 129)] = lo;
    }
  }
}

// ---------- prep: xw[r] = x[r][N]
__global__ __launch_bounds__(256)
void kPrepXw(const float* __restrict__ x, float* __restrict__ xw) {
  int r = blockIdx.x * 256 + TID;
  xw[r] = x[(size_t)r * XP + N_IN];
}

// ---------- kernel A: xa partials = x @ W_down, bf16-split MFMA, K-split 8
// grid (64 row-tiles, 8 splits), 256 threads; wave tile 32 rows x 128 cols
__global__ __launch_bounds__(256)
void kA_mfma(const float* __restrict__ x, const bf16_t* __restrict__ Whi,
             const bf16_t* __restrict__ Wlo, float* __restrict__ parts) {
  __shared__ bf16_t Bt[2][128][64];
  const int lane = TID & 63, w = TID >> 6;
  const int row0 = blockIdx.x * 128 + w * 32;
  const int s = blockIdx.y;
  const int kbase = s * KCHUNK;
  floatx4 acc[2][8] = {};
  for (int kt = 0; kt < KCHUNK / 64; ++kt) {
    const int k0 = kbase + kt * 64;
    // stage B tile (hi+lo), XOR-swizzled k-groups so ds_read_b128 hits the 8-slot floor
    #pragma unroll
    for (int i = 0; i < 8; ++i) {
      int f = TID + 256 * i;
      int arr = f >> 10, rem = f & 1023;
      int col = rem >> 3, g = rem & 7;
      int gs = g ^ (col & 7);
      const bf16_t* src = (arr ? Wlo : Whi) + (size_t)col * KPD + k0 + gs * 8;
      *(uint4*)&Bt[arr][col][g * 8] = *(const uint4*)src;
    }
    __syncthreads();
    #pragma unroll
    for (int h = 0; h < 2; ++h) {
      const int kk0 = k0 + h * 32 + (lane >> 4) * 8;
      bf16x8 ahi[2], alo[2];
      #pragma unroll
      for (int rf = 0; rf < 2; ++rf) {
        const float* xp = x + (size_t)(row0 + rf * 16 + (lane & 15)) * XP + kk0;
        #pragma unroll
        for (int e = 0; e < 8; ++e) {
          float v = (kk0 + e < N_IN) ? xp[e] : 0.0f;
          bf16_t hi = (bf16_t)v;
          ahi[rf][e] = hi;
          alo[rf][e] = (bf16_t)(v - (float)hi);
        }
      }
      #pragma unroll
      for (int cf = 0; cf < 8; ++cf) {
        const int col = cf * 16 + (lane & 15);
        const int p = ((h * 4) + (lane >> 4)) ^ (col & 7);
        bf16x8 bhi = *(const bf16x8*)&Bt[0][col][p * 8];
        bf16x8 blo = *(const bf16x8*)&Bt[1][col][p * 8];
        #pragma unroll
        for (int rf = 0; rf < 2; ++rf) {
          acc[rf][cf] = MFMA(ahi[rf], bhi, acc[rf][cf]);
          acc[rf][cf] = MFMA(ahi[rf], blo, acc[rf][cf]);
          acc[rf][cf] = MFMA(alo[rf], bhi, acc[rf][cf]);
        }
      }
    }
    __syncthreads();
  }
  float* dst = parts + (size_t)s * MROW * 128;
  #pragma unroll
  for (int rf = 0; rf < 2; ++rf)
    #pragma unroll
    for (int cf = 0; cf < 8; ++cf)
      #pragma unroll
      for (int r = 0; r < 4; ++r) {
        int row = row0 + rf * 16 + (lane >> 4) * 4 + r;
        int col = cf * 16 + (lane & 15);
        dst[(size_t)row * 128 + col] = acc[rf][cf][r];
      }
}

// ---------- reduce partials -> xa [8192][128]
__global__ __launch_bounds__(256)
void kRed(const float* __restrict__ parts, float* __restrict__ xa) {
  size_t i4 = ((size_t)blockIdx.x * 256 + TID) * 4;
  float4 v = make_float4(0.f, 0.f, 0.f, 0.f);
  #pragma unroll
  for (int s = 0; s < KSPLIT; ++s) {
    float4 p = *(const float4*)&parts[(size_t)s * MROW * 128 + i4];
    v.x += p.x; v.y += p.y; v.z += p.z; v.w += p.w;
  }
  *(float4*)&xa[i4] = v;
}

// ---------- one LSTM step: gates = [xa(128) | h(512)] @ [WxT;WhT] + bc + xw*wN; pointwise
// grid (32 j-tiles, 4 row-tiles), 256 threads; wave tile 32 b-rows x (16 j x 4 gates)
__global__ __launch_bounds__(256)
void kStep(const float* __restrict__ xa, const float* __restrict__ xw,
           const bf16_t* __restrict__ Wxh, const bf16_t* __restrict__ Wxl,
           const bf16_t* __restrict__ Whh, const bf16_t* __restrict__ Whl,
           const float* __restrict__ wN, const float* __restrict__ bc,
           const float* __restrict__ h_in, const float* __restrict__ c_in,
           float* __restrict__ h_out, float* __restrict__ c_out,
           int t, int has_h) {
  __shared__ bf16_t Bt[2][64][64];
  const int lane = TID & 63, w = TID >> 6;
  const int j0 = blockIdx.x * 16;
  const int brow0 = blockIdx.y * 128 + w * 32;
  floatx4 acc[2][4] = {};
  const int ntiles = has_h ? 10 : 2;
  for (int kt = 0; kt < ntiles; ++kt) {
    const int k0 = kt * 64;
    // stage B tile: cols = 4 gates x 16 j, from WxT (k<128) or WhT
    #pragma unroll
    for (int i = 0; i < 4; ++i) {
      int f = TID + 256 * i;
      int arr = f >> 9, rem = f & 511;
      int ce = rem >> 3, g = rem & 7;
      int g4 = ce >> 4, jl = ce & 15;
      int c = g4 * 512 + j0 + jl;
      int gs = g ^ (ce & 7);
      const bf16_t* src;
      if (k0 < 128) src = (arr ? Wxl : Wxh) + (size_t)c * 128 + k0 + gs * 8;
      else          src = (arr ? Whl : Whh) + (size_t)c * 512 + (k0 - 128) + gs * 8;
      *(uint4*)&Bt[arr][ce][g * 8] = *(const uint4*)src;
    }
    __syncthreads();
    #pragma unroll
    for (int h = 0; h < 2; ++h) {
      const int kk0 = k0 + h * 32 + (lane >> 4) * 8;
      bf16x8 ahi[2], alo[2];
      #pragma unroll
      for (int rf = 0; rf < 2; ++rf) {
        const int b = brow0 + rf * 16 + (lane & 15);
        const float* ap = (k0 < 128) ? xa + ((size_t)b * TT + t) * 128 + kk0
                                     : h_in + (size_t)b * HH + (kk0 - 128);
        float4 v0 = *(const float4*)ap;
        float4 v1 = *(const float4*)(ap + 4);
        float vv[8] = {v0.x, v0.y, v0.z, v0.w, v1.x, v1.y, v1.z, v1.w};
        #pragma unroll
        for (int e = 0; e < 8; ++e) {
          bf16_t hi = (bf16_t)vv[e];
          ahi[rf][e] = hi;
          alo[rf][e] = (bf16_t)(vv[e] - (float)hi);
        }
      }
      #pragma unroll
      for (int cf = 0; cf < 4; ++cf) {
        const int ce = cf * 16 + (lane & 15);
        const int p = ((h * 4) + (lane >> 4)) ^ (ce & 7);
        bf16x8 bhi = *(const bf16x8*)&Bt[0][ce][p * 8];
        bf16x8 blo = *(const bf16x8*)&Bt[1][ce][p * 8];
        #pragma unroll
        for (int rf = 0; rf < 2; ++rf) {
          acc[rf][cf] = MFMA(ahi[rf], bhi, acc[rf][cf]);
          acc[rf][cf] = MFMA(ahi[rf], blo, acc[rf][cf]);
          acc[rf][cf] = MFMA(alo[rf], bhi, acc[rf][cf]);
        }
      }
    }
    __syncthreads();
  }
  // epilogue: all 4 gates of j are lane-local (cf = gate)
  const int j = j0 + (lane & 15);
  #pragma unroll
  for (int rf = 0; rf < 2; ++rf)
    #pragma unroll
    for (int r = 0; r < 4; ++r) {
      int b = brow0 + rf * 16 + (lane >> 4) * 4 + r;
      float xwv = xw[b * TT + t];
      float gi = acc[rf][0][r] + bc[j]        + xwv * wN[j];
      float gc = acc[rf][1][r] + bc[512 + j]  + xwv * wN[512 + j];
      float gf = acc[rf][2][r] + bc[1024 + j] + xwv * wN[1024 + j];
      float go = acc[rf][3][r] + bc[1536 + j] + xwv * wN[1536 + j];
      float cp = has_h ? c_in[(size_t)b * HH + j] : 0.0f;
      float cn = cp * sigm(gf + 1.0f) + sigm(gi) * tanhf(gc);
      float hn = sigm(go) * tanhf(cn);
      c_out[(size_t)b * HH + j] = cn;
      h_out[(size_t)b * HH + j] = hn;
    }
}

// ---------- output projection
__global__ __launch_bounds__(64)
void kC_out(const float* __restrict__ h, const float* __restrict__ Wo,
            const float* __restrict__ bo, float* __restrict__ out) {
  const int b = blockIdx.x;
  float s = 0.0f;
  for (int j = TID; j < HH; j += 64) s += h[(size_t)b * HH + j] * Wo[j];
  #pragma unroll
  for (int off = 32; off > 0; off >>= 1) s += __shfl_down(s, off);
  if (TID == 0) out[b] = s + bo[0];
}

extern "C" void kernel_launch(void* const* d_in, const int* in_sizes, int n_in,
                              void* d_out, int out_size, void* d_ws, size_t ws_size,
                              hipStream_t stream) {
  const float* x  = (const float*)d_in[0];
  const float* Wd = (const float*)d_in[1];
  const float* Wc = (const float*)d_in[2];
  const float* bc = (const float*)d_in[3];
  const float* Wo = (const float*)d_in[4];
  const float* bo = (const float*)d_in[5];
  float* out = (float*)d_out;

  char* w = (char*)d_ws;
  size_t off = 0;
  auto alloc = [&](size_t bytes) -> void* {
    void* p = w + off;
    off = (off + bytes + 255) & ~(size_t)255;
    return p;
  };
  bf16_t* WdThi = (bf16_t*)alloc((size_t)128 * KPD * 2);
  bf16_t* WdTlo = (bf16_t*)alloc((size_t)128 * KPD * 2);
  bf16_t* WxThi = (bf16_t*)alloc((size_t)2048 * 128 * 2);
  bf16_t* WxTlo = (bf16_t*)alloc((size_t)2048 * 128 * 2);
  bf16_t* WhThi = (bf16_t*)alloc((size_t)2048 * 512 * 2);
  bf16_t* WhTlo = (bf16_t*)alloc((size_t)2048 * 512 * 2);
  float*  wN    = (float*)alloc(2048 * 4);
  float*  xw    = (float*)alloc(MROW * 4);
  float*  parts = (float*)alloc((size_t)KSPLIT * MROW * 128 * 4);
  float*  xa    = (float*)alloc((size_t)MROW * 128 * 4);
  float*  h0    = (float*)alloc((size_t)NB * HH * 4);
  float*  h1    = (float*)alloc((size_t)NB * HH * 4);
  float*  c0    = (float*)alloc((size_t)NB * HH * 4);
  float*  c1    = (float*)alloc((size_t)NB * HH * 4);
  float*  hb[2] = {h0, h1};
  float*  cb[2] = {c0, c1};

  kPrepWd<<<160, 256, 0, stream>>>(Wd, WdThi, WdTlo);
  kPrepWc<<<dim3(11, 16), 256, 0, stream>>>(Wc, WxThi, WxTlo, wN, WhThi, WhTlo);
  kPrepXw<<<32, 256, 0, stream>>>(x, xw);
  kA_mfma<<<dim3(64, KSPLIT), 256, 0, stream>>>(x, WdThi, WdTlo, parts);
  kRed<<<1024, 256, 0, stream>>>(parts, xa);
  for (int t = 0; t < TT; ++t) {
    kStep<<<dim3(32, 4), 256, 0, stream>>>(xa, xw, WxThi, WxTlo, WhThi, WhTlo, wN, bc,
        hb[t & 1], cb[t & 1], hb[(t + 1) & 1], cb[(t + 1) & 1], t, (t == 0) ? 0 : 1);
  }
  kC_out<<<512, 64, 0, stream>>>(hb[0], Wo, bo, out);
}

// Round 3
// 467.289 us; speedup vs baseline: 6.5293x; 1.4158x over previous
//
#include <hip/hip_runtime.h>
#include <cmath>

#define TID ((int)threadIdx.x)

typedef __bf16 bf16_t;
typedef bf16_t bf16x8 __attribute__((ext_vector_type(8)));
typedef float floatx4 __attribute__((ext_vector_type(4)));

#define MFMA(a, b, c) __builtin_amdgcn_mfma_f32_16x16x32_bf16(a, b, c, 0, 0, 0)

constexpr int N_IN = 10000;
constexpr int XP   = 10001;   // x row pitch
constexpr int KPD  = 10240;   // padded K for W_down^T
constexpr int HH   = 512;
constexpr int TT   = 16;
constexpr int NB   = 512;
constexpr int MROW = 8192;    // NB*TT
constexpr int KSPLIT = 16;
constexpr int KCHUNK = 640;   // KPD/KSPLIT
constexpr int KT_A = 10;      // KCHUNK/64

__device__ __forceinline__ float sigm(float x) { return 1.0f / (1.0f + expf(-x)); }

__device__ __forceinline__ void gload16(const void* g, void* lds) {
  __builtin_amdgcn_global_load_lds(
      (const __attribute__((address_space(1))) unsigned int*)g,
      (__attribute__((address_space(3))) unsigned int*)lds, 16, 0, 0);
}

// ---------- prep: W_down (10000x128 fp32) -> WdT hi/lo bf16 [128][10240]
__global__ __launch_bounds__(256)
void kPrepWd(const float* __restrict__ Wd, bf16_t* __restrict__ Whi, bf16_t* __restrict__ Wlo) {
  __shared__ float Ts[64][133];
  const int k0 = blockIdx.x * 64;
  #pragma unroll
  for (int i = 0; i < 32; ++i) {
    int f = TID + 256 * i;
    int kk = f >> 7, c = f & 127;
    int k = k0 + kk;
    Ts[kk][c] = (k < N_IN) ? Wd[(size_t)k * 128 + c] : 0.0f;
  }
  __syncthreads();
  const int lane = TID & 63, w = TID >> 6;
  for (int pass = 0; pass < 32; ++pass) {
    int c = pass * 4 + w;
    float v = Ts[lane][c];
    bf16_t hi = (bf16_t)v;
    bf16_t lo = (bf16_t)(v - (float)hi);
    Whi[(size_t)c * KPD + k0 + lane] = hi;
    Wlo[(size_t)c * KPD + k0 + lane] = lo;
  }
}

// ---------- prep: W_cell (641x2048) -> WxT[2048][128], wN[2048], WhT[2048][512] (hi/lo)
__global__ __launch_bounds__(256)
void kPrepWc(const float* __restrict__ Wc, bf16_t* __restrict__ Wxh, bf16_t* __restrict__ Wxl,
             float* __restrict__ wN, bf16_t* __restrict__ Whh, bf16_t* __restrict__ Whl) {
  __shared__ float Ts[64][133];
  const int k0 = blockIdx.x * 64;
  const int c0 = blockIdx.y * 128;
  #pragma unroll
  for (int i = 0; i < 32; ++i) {
    int f = TID + 256 * i;
    int kk = f >> 7, cc = f & 127;
    int k = k0 + kk;
    Ts[kk][cc] = (k < 641) ? Wc[(size_t)k * 2048 + c0 + cc] : 0.0f;
  }
  __syncthreads();
  const int lane = TID & 63, w = TID >> 6;
  const int k = k0 + lane;
  for (int pass = 0; pass < 32; ++pass) {
    int cc = pass * 4 + w;
    int c = c0 + cc;
    float v = Ts[lane][cc];
    bf16_t hi = (bf16_t)v;
    bf16_t lo = (bf16_t)(v - (float)hi);
    if (k < 128) {
      Wxh[(size_t)c * 128 + k] = hi;
      Wxl[(size_t)c * 128 + k] = lo;
    } else if (k == 128) {
      wN[c] = v;
    } else if (k < 641) {
      Whh[(size_t)c * 512 + (k - 129)] = hi;
      Whl[(size_t)c * 512 + (k - 129)] = lo;
    }
  }
}

// ---------- prep: xw[r] = x[r][N]
__global__ __launch_bounds__(256)
void kPrepXw(const float* __restrict__ x, float* __restrict__ xw) {
  int r = blockIdx.x * 256 + TID;
  xw[r] = x[(size_t)r * XP + N_IN];
}

// ---------- kernel A: parts[s] = x @ W_down chunk, bf16 3-pass MFMA
// grid (64 row-tiles, 16 splits), 256 thr / 4 waves; wave 32 rows x 128 cols
// 2-phase: global_load_lds B double-buffer + reg-prefetched x
__global__ __launch_bounds__(256, 2)
void kA_mfma(const float* __restrict__ x, const bf16_t* __restrict__ Whi,
             const bf16_t* __restrict__ Wlo, float* __restrict__ parts) {
  // chunk L = arr*1024 + col*8 + g (16B each); linear dest, pre-swizzled source
  __shared__ __align__(16) bf16_t Bt[2][2048 * 8];
  const int lane = TID & 63, w = TID >> 6;
  const int row0 = blockIdx.x * 128 + w * 32;
  const int kbase = blockIdx.y * KCHUNK;
  floatx4 acc[2][8] = {};

  auto STAGE = [&](int buf, int kt) {
    const int k0 = kbase + kt * 64;
    #pragma unroll
    for (int i = 0; i < 8; ++i) {
      int L = i * 256 + TID;
      int arr = L >> 10, col = (L >> 3) & 127, g = L & 7;
      int gs = g ^ (col & 7);
      const bf16_t* src = (arr ? Wlo : Whi) + (size_t)col * KPD + k0 + gs * 8;
      gload16(src, &Bt[buf][(size_t)L * 8]);
    }
  };
  auto LOADX = [&](float4 (&xb)[2][2][2], int kt) {
    const int k0 = kbase + kt * 64;
    #pragma unroll
    for (int rf = 0; rf < 2; ++rf) {
      const float* xp = x + (size_t)(row0 + rf * 16 + (lane & 15)) * XP;
      #pragma unroll
      for (int h = 0; h < 2; ++h) {
        int kk0 = k0 + h * 32 + (lane >> 4) * 8;
        if (kk0 < N_IN) {   // N_IN is a multiple of 8, so all-or-nothing
          xb[rf][h][0] = *(const float4*)(xp + kk0);
          xb[rf][h][1] = *(const float4*)(xp + kk0 + 4);
        } else {
          xb[rf][h][0] = make_float4(0.f, 0.f, 0.f, 0.f);
          xb[rf][h][1] = make_float4(0.f, 0.f, 0.f, 0.f);
        }
      }
    }
  };
  auto COMPUTE = [&](int buf, const float4 (&xb)[2][2][2]) {
    #pragma unroll
    for (int h = 0; h < 2; ++h) {
      const int p = h * 4 + (lane >> 4);
      bf16x8 ahi[2], alo[2];
      #pragma unroll
      for (int rf = 0; rf < 2; ++rf) {
        float vv[8] = {xb[rf][h][0].x, xb[rf][h][0].y, xb[rf][h][0].z, xb[rf][h][0].w,
                       xb[rf][h][1].x, xb[rf][h][1].y, xb[rf][h][1].z, xb[rf][h][1].w};
        #pragma unroll
        for (int e = 0; e < 8; ++e) {
          bf16_t hi = (bf16_t)vv[e];
          ahi[rf][e] = hi;
          alo[rf][e] = (bf16_t)(vv[e] - (float)hi);
        }
      }
      #pragma unroll
      for (int cf = 0; cf < 8; ++cf) {
        const int col = cf * 16 + (lane & 15);
        const int g = p ^ (col & 7);
        bf16x8 bhi = *(const bf16x8*)&Bt[buf][(col * 8 + g) * 8];
        bf16x8 blo = *(const bf16x8*)&Bt[buf][(1024 + col * 8 + g) * 8];
        #pragma unroll
        for (int rf = 0; rf < 2; ++rf) {
          acc[rf][cf] = MFMA(ahi[rf], bhi, acc[rf][cf]);
          acc[rf][cf] = MFMA(ahi[rf], blo, acc[rf][cf]);
          acc[rf][cf] = MFMA(alo[rf], bhi, acc[rf][cf]);
        }
      }
    }
  };

  float4 xbA[2][2][2], xbB[2][2][2];
  STAGE(0, 0);
  LOADX(xbA, 0);
  __syncthreads();
  #pragma unroll
  for (int kt = 0; kt < KT_A; kt += 2) {
    if (kt + 1 < KT_A) { STAGE(1, kt + 1); LOADX(xbB, kt + 1); }
    COMPUTE(0, xbA);
    __syncthreads();
    if (kt + 2 < KT_A) { STAGE(0, kt + 2); LOADX(xbA, kt + 2); }
    COMPUTE(1, xbB);
    __syncthreads();
  }

  float* dst = parts + (size_t)blockIdx.y * MROW * 128;
  #pragma unroll
  for (int rf = 0; rf < 2; ++rf)
    #pragma unroll
    for (int cf = 0; cf < 8; ++cf)
      #pragma unroll
      for (int r = 0; r < 4; ++r) {
        int row = row0 + rf * 16 + (lane >> 4) * 4 + r;
        int col = cf * 16 + (lane & 15);
        dst[(size_t)row * 128 + col] = acc[rf][cf][r];
      }
}

// ---------- reduce partials -> xa [8192][128]
__global__ __launch_bounds__(256)
void kRed(const float* __restrict__ parts, float* __restrict__ xa) {
  size_t i4 = ((size_t)blockIdx.x * 256 + TID) * 4;
  float4 v = make_float4(0.f, 0.f, 0.f, 0.f);
  #pragma unroll
  for (int s = 0; s < KSPLIT; ++s) {
    float4 p = *(const float4*)&parts[(size_t)s * MROW * 128 + i4];
    v.x += p.x; v.y += p.y; v.z += p.z; v.w += p.w;
  }
  *(float4*)&xa[i4] = v;
}

// ---------- gx = xa @ Wx + bc + xw*wN, layout gx[row][j*4+g]
// grid (64 row-tiles, 16 col-tiles), 512 thr / 8 waves (4 row x 2 col), wave 32x64
__global__ __launch_bounds__(512, 2)
void kGx(const float* __restrict__ xa, const float* __restrict__ xw,
         const bf16_t* __restrict__ Wxh, const bf16_t* __restrict__ Wxl,
         const float* __restrict__ wN, const float* __restrict__ bc,
         float* __restrict__ gx) {
  // chunk L = arr*2048 + ce*16 + g (16 k-groups cover K=128)
  __shared__ __align__(16) bf16_t Bt[4096 * 8];
  const int lane = TID & 63, w = TID >> 6;
  const int wr = w & 3, wc = w >> 2;
  const int rowbase = blockIdx.x * 128 + wr * 32;
  const int JB = blockIdx.y * 32;
  floatx4 acc[2][4] = {};

  // stage whole K=128 B tile (hi+lo): 4096 chunks / 512 thr = 8 each
  #pragma unroll
  for (int i = 0; i < 8; ++i) {
    int L = i * 512 + TID;
    int arr = L >> 11, ce = (L >> 4) & 127, g = L & 15;
    int gs = g ^ (ce & 15);
    int c_src = (ce & 3) * 512 + JB + (ce >> 2);
    const bf16_t* src = (arr ? Wxl : Wxh) + (size_t)c_src * 128 + gs * 8;
    gload16(src, &Bt[(size_t)L * 8]);
  }
  // load all A (K=128) while B stages
  float4 xb[2][2][2][2];  // [kt][rf][h][half]
  #pragma unroll
  for (int kt = 0; kt < 2; ++kt)
    #pragma unroll
    for (int rf = 0; rf < 2; ++rf) {
      const float* ap = xa + (size_t)(rowbase + rf * 16 + (lane & 15)) * 128;
      #pragma unroll
      for (int h = 0; h < 2; ++h) {
        int kk0 = kt * 64 + h * 32 + (lane >> 4) * 8;
        xb[kt][rf][h][0] = *(const float4*)(ap + kk0);
        xb[kt][rf][h][1] = *(const float4*)(ap + kk0 + 4);
      }
    }
  __syncthreads();
  #pragma unroll
  for (int kt = 0; kt < 2; ++kt) {
    #pragma unroll
    for (int h = 0; h < 2; ++h) {
      const int p = kt * 8 + h * 4 + (lane >> 4);
      bf16x8 ahi[2], alo[2];
      #pragma unroll
      for (int rf = 0; rf < 2; ++rf) {
        float vv[8] = {xb[kt][rf][h][0].x, xb[kt][rf][h][0].y, xb[kt][rf][h][0].z, xb[kt][rf][h][0].w,
                       xb[kt][rf][h][1].x, xb[kt][rf][h][1].y, xb[kt][rf][h][1].z, xb[kt][rf][h][1].w};
        #pragma unroll
        for (int e = 0; e < 8; ++e) {
          bf16_t hi = (bf16_t)vv[e];
          ahi[rf][e] = hi;
          alo[rf][e] = (bf16_t)(vv[e] - (float)hi);
        }
      }
      #pragma unroll
      for (int cf = 0; cf < 4; ++cf) {
        const int ce = wc * 64 + cf * 16 + (lane & 15);
        const int g = p ^ (ce & 15);
        bf16x8 bhi = *(const bf16x8*)&Bt[(ce * 16 + g) * 8];
        bf16x8 blo = *(const bf16x8*)&Bt[(2048 + ce * 16 + g) * 8];
        #pragma unroll
        for (int rf = 0; rf < 2; ++rf) {
          acc[rf][cf] = MFMA(ahi[rf], bhi, acc[rf][cf]);
          acc[rf][cf] = MFMA(ahi[rf], blo, acc[rf][cf]);
          acc[rf][cf] = MFMA(alo[rf], bhi, acc[rf][cf]);
        }
      }
    }
  }
  #pragma unroll
  for (int rf = 0; rf < 2; ++rf)
    #pragma unroll
    for (int cf = 0; cf < 4; ++cf) {
      const int ce = wc * 64 + cf * 16 + (lane & 15);
      const int n = blockIdx.y * 128 + ce;
      const int c_src = (ce & 3) * 512 + JB + (ce >> 2);
      const float bias = bc[c_src];
      const float wn = wN[c_src];
      #pragma unroll
      for (int r = 0; r < 4; ++r) {
        int row = rowbase + rf * 16 + (lane >> 4) * 4 + r;
        gx[(size_t)row * 2048 + n] = acc[rf][cf][r] + bias + xw[row] * wn;
      }
    }
}

// ---------- one LSTM step: gates = h @ WhT + gx; pointwise; h out as bf16 hi/lo
// grid (32 j-tiles, 8 row-tiles), 128 thr / 2 waves; wave 32 rows x 64 cols (cf=gate)
__global__ __launch_bounds__(128, 2)
void kStepH(const bf16_t* __restrict__ hhi_in, const bf16_t* __restrict__ hlo_in,
            const bf16_t* __restrict__ Whh, const bf16_t* __restrict__ Whl,
            const float* __restrict__ gx, const float* __restrict__ c_in,
            bf16_t* __restrict__ hhi_out, bf16_t* __restrict__ hlo_out,
            float* __restrict__ c_out, int t, int has_h) {
  __shared__ __align__(16) bf16_t Bt[2][1024 * 8];  // L = arr*512 + ce*8 + g
  const int lane = TID & 63, w = TID >> 6;
  const int j0 = blockIdx.x * 16;
  const int brow0 = blockIdx.y * 64 + w * 32;
  floatx4 acc[2][4] = {};

  auto STAGE = [&](int buf, int kt) {
    const int k0 = kt * 64;
    #pragma unroll
    for (int i = 0; i < 8; ++i) {
      int L = i * 128 + TID;
      int arr = L >> 9, ce = (L >> 3) & 63, g = L & 7;
      int gs = g ^ (ce & 7);
      int c_src = (ce >> 4) * 512 + j0 + (ce & 15);
      const bf16_t* src = (arr ? Whl : Whh) + (size_t)c_src * 512 + k0 + gs * 8;
      gload16(src, &Bt[buf][(size_t)L * 8]);
    }
  };
  auto LOADA = [&](bf16x8 (&ar)[2][2][2], int kt) {
    #pragma unroll
    for (int rf = 0; rf < 2; ++rf) {
      const int b = brow0 + rf * 16 + (lane & 15);
      #pragma unroll
      for (int h = 0; h < 2; ++h) {
        const int kk0 = kt * 64 + h * 32 + (lane >> 4) * 8;
        ar[rf][h][0] = *(const bf16x8*)&hhi_in[(size_t)b * HH + kk0];
        ar[rf][h][1] = *(const bf16x8*)&hlo_in[(size_t)b * HH + kk0];
      }
    }
  };
  auto COMPUTE = [&](int buf, const bf16x8 (&ar)[2][2][2]) {
    #pragma unroll
    for (int h = 0; h < 2; ++h) {
      const int p = h * 4 + (lane >> 4);
      #pragma unroll
      for (int cf = 0; cf < 4; ++cf) {
        const int ce = cf * 16 + (lane & 15);
        const int g = p ^ (ce & 7);
        bf16x8 bhi = *(const bf16x8*)&Bt[buf][(ce * 8 + g) * 8];
        bf16x8 blo = *(const bf16x8*)&Bt[buf][(512 + ce * 8 + g) * 8];
        #pragma unroll
        for (int rf = 0; rf < 2; ++rf) {
          acc[rf][cf] = MFMA(ar[rf][h][0], bhi, acc[rf][cf]);
          acc[rf][cf] = MFMA(ar[rf][h][0], blo, acc[rf][cf]);
          acc[rf][cf] = MFMA(ar[rf][h][1], bhi, acc[rf][cf]);
        }
      }
    }
  };

  if (has_h) {
    bf16x8 aA[2][2][2], aB[2][2][2];
    STAGE(0, 0);
    LOADA(aA, 0);
    __syncthreads();
    #pragma unroll
    for (int kt = 0; kt < 8; kt += 2) {
      if (kt + 1 < 8) { STAGE(1, kt + 1); LOADA(aB, kt + 1); }
      COMPUTE(0, aA);
      __syncthreads();
      if (kt + 2 < 8) { STAGE(0, kt + 2); LOADA(aA, kt + 2); }
      COMPUTE(1, aB);
      __syncthreads();
    }
  }

  const int jl = lane & 15;
  const int j = j0 + jl;
  #pragma unroll
  for (int rf = 0; rf < 2; ++rf)
    #pragma unroll
    for (int r = 0; r < 4; ++r) {
      int b = brow0 + rf * 16 + (lane >> 4) * 4 + r;
      float4 gv = *(const float4*)&gx[((size_t)b * TT + t) * 2048 + (size_t)j * 4];
      float gi = acc[rf][0][r] + gv.x;
      float gc = acc[rf][1][r] + gv.y;
      float gf = acc[rf][2][r] + gv.z;
      float go = acc[rf][3][r] + gv.w;
      float cp = has_h ? c_in[(size_t)b * HH + j] : 0.0f;
      float cn = cp * sigm(gf + 1.0f) + sigm(gi) * tanhf(gc);
      float hn = sigm(go) * tanhf(cn);
      c_out[(size_t)b * HH + j] = cn;
      bf16_t hh = (bf16_t)hn;
      hhi_out[(size_t)b * HH + j] = hh;
      hlo_out[(size_t)b * HH + j] = (bf16_t)(hn - (float)hh);
    }
}

// ---------- output projection (h = hi + lo)
__global__ __launch_bounds__(64)
void kC_out(const bf16_t* __restrict__ hh, const bf16_t* __restrict__ hl,
            const float* __restrict__ Wo, const float* __restrict__ bo,
            float* __restrict__ out) {
  const int b = blockIdx.x;
  float s = 0.0f;
  for (int j = TID; j < HH; j += 64)
    s += ((float)hh[(size_t)b * HH + j] + (float)hl[(size_t)b * HH + j]) * Wo[j];
  #pragma unroll
  for (int off = 32; off > 0; off >>= 1) s += __shfl_down(s, off);
  if (TID == 0) out[b] = s + bo[0];
}

extern "C" void kernel_launch(void* const* d_in, const int* in_sizes, int n_in,
                              void* d_out, int out_size, void* d_ws, size_t ws_size,
                              hipStream_t stream) {
  const float* x  = (const float*)d_in[0];
  const float* Wd = (const float*)d_in[1];
  const float* Wc = (const float*)d_in[2];
  const float* bc = (const float*)d_in[3];
  const float* Wo = (const float*)d_in[4];
  const float* bo = (const float*)d_in[5];
  float* out = (float*)d_out;

  char* wsb = (char*)d_ws;
  size_t off = 0;
  auto alloc = [&](size_t bytes) -> void* {
    void* p = wsb + off;
    off = (off + bytes + 255) & ~(size_t)255;
    return p;
  };
  bf16_t* WdThi = (bf16_t*)alloc((size_t)128 * KPD * 2);
  bf16_t* WdTlo = (bf16_t*)alloc((size_t)128 * KPD * 2);
  bf16_t* WxThi = (bf16_t*)alloc((size_t)2048 * 128 * 2);
  bf16_t* WxTlo = (bf16_t*)alloc((size_t)2048 * 128 * 2);
  bf16_t* WhThi = (bf16_t*)alloc((size_t)2048 * 512 * 2);
  bf16_t* WhTlo = (bf16_t*)alloc((size_t)2048 * 512 * 2);
  float*  wN    = (float*)alloc(2048 * 4);
  float*  xw    = (float*)alloc(MROW * 4);
  float*  xa    = (float*)alloc((size_t)MROW * 128 * 4);
  float*  parts = (float*)alloc((size_t)KSPLIT * MROW * 128 * 4);  // 64MB, reused as gx
  float*  gx    = parts;                                           // alias: parts dead after kRed
  bf16_t* hhi[2] = {(bf16_t*)alloc((size_t)NB * HH * 2), (bf16_t*)alloc((size_t)NB * HH * 2)};
  bf16_t* hlo[2] = {(bf16_t*)alloc((size_t)NB * HH * 2), (bf16_t*)alloc((size_t)NB * HH * 2)};
  float*  cb[2]  = {(float*)alloc((size_t)NB * HH * 4), (float*)alloc((size_t)NB * HH * 4)};

  kPrepWd<<<160, 256, 0, stream>>>(Wd, WdThi, WdTlo);
  kPrepWc<<<dim3(11, 16), 256, 0, stream>>>(Wc, WxThi, WxTlo, wN, WhThi, WhTlo);
  kPrepXw<<<32, 256, 0, stream>>>(x, xw);
  kA_mfma<<<dim3(64, KSPLIT), 256, 0, stream>>>(x, WdThi, WdTlo, parts);
  kRed<<<1024, 256, 0, stream>>>(parts, xa);
  kGx<<<dim3(64, 16), 512, 0, stream>>>(xa, xw, WxThi, WxTlo, wN, bc, gx);
  for (int t = 0; t < TT; ++t) {
    kStepH<<<dim3(32, 8), 128, 0, stream>>>(hhi[t & 1], hlo[t & 1], WhThi, WhTlo,
        gx, cb[t & 1], hhi[(t + 1) & 1], hlo[(t + 1) & 1], cb[(t + 1) & 1],
        t, (t == 0) ? 0 : 1);
  }
  kC_out<<<512, 64, 0, stream>>>(hhi[0], hlo[0], Wo, bo, out);
}